// Round 9
// baseline (288.472 us; speedup 1.0000x reference)
//
#include <hip/hip_runtime.h>
#include <hip/hip_bf16.h>
#include <stdint.h>

#define IN_CH 794
#define KPAD  832            // 26 * 32 = 13 * 64
#define Z1C   1024
#define OUT_C 512
#define BATCH 32768

typedef __attribute__((ext_vector_type(8))) short short8;
typedef __attribute__((ext_vector_type(4))) float f32x4;

__device__ __forceinline__ ushort f2bf(float f) {
  uint32_t u = __float_as_uint(f);
  return (ushort)((u + 0x7fffu + ((u >> 16) & 1u)) >> 16);  // RTNE
}

__device__ __forceinline__ void glds16(const void* g, void* l) {
  __builtin_amdgcn_global_load_lds(
      (const __attribute__((address_space(1))) void*)g,
      (__attribute__((address_space(3))) void*)l, 16, 0, 0);
}

#define MFMA(a, b, c) __builtin_amdgcn_mfma_f32_16x16x32_bf16(a, b, c, 0, 0, 0)

// ---------------- prep: masked weights (bf16) + folded bias ----------------
__global__ __launch_bounds__(256) void prep1(
    const float* __restrict__ W1, const float* __restrict__ b1,
    const float* __restrict__ Wc1, const float* __restrict__ bc1,
    const float* __restrict__ MW0, ushort* __restrict__ w1p,
    float* __restrict__ bias1) {
  int z = blockIdx.x, t = threadIdx.x;
  float sum = 0.f;
  for (int i = t; i < KPAD; i += 256) {
    float w = 0.f;
    if (i < IN_CH) {
      float m = MW0[z * IN_CH + i];
      w = W1[z * IN_CH + i] * m;
      sum += Wc1[z * IN_CH + i] * m;
    }
    w1p[z * KPAD + i] = f2bf(w);
  }
#pragma unroll
  for (int o = 32; o > 0; o >>= 1) sum += __shfl_down(sum, o, 64);
  __shared__ float red[4];
  if ((t & 63) == 0) red[t >> 6] = sum;
  __syncthreads();
  if (t == 0) bias1[z] = b1[z] + bc1[z] + red[0] + red[1] + red[2] + red[3];
}

__global__ __launch_bounds__(256) void prep2(
    const float* __restrict__ W2, const float* __restrict__ b2,
    const float* __restrict__ Wc2, const float* __restrict__ bc2,
    const float* __restrict__ MW1, ushort* __restrict__ w2m,
    float* __restrict__ bias2) {
  int z = blockIdx.x, t = threadIdx.x;
  float sum = 0.f;
  for (int i = t; i < Z1C; i += 256) {
    float m = MW1[z * Z1C + i];
    w2m[z * Z1C + i] = f2bf(W2[z * Z1C + i] * m);
    sum += Wc2[z * Z1C + i] * m;
  }
#pragma unroll
  for (int o = 32; o > 0; o >>= 1) sum += __shfl_down(sum, o, 64);
  __shared__ float red[4];
  if ((t & 63) == 0) red[t >> 6] = sum;
  __syncthreads();
  if (t == 0) bias2[z] = b2[z] + bc2[z] + red[0] + red[1] + red[2] + red[3];
}

// =================== fused MADE: out = relu(relu(x@W1'^T+b1')@W2'^T+b2') ===================
// 256 blocks (1/CU), 512 thr (8 waves 2Mx4N). Block owns 128 batch rows.
// __launch_bounds__(512, 1): LDS (160 KiB) already caps at 1 block/CU; the
// previous (512,2) capped unified regs at 256/wave while acc2+acc1 alone need
// 192 AGPR -> hot-loop spill (r7/r8 FETCH/WRITE excess). At 1 wave/EU the
// allocator gets 512 regs; worst ledger ~322. Zero spill expected.
// Per chunk c (4 chunks of 256 h1-cols):
//   stage1: 13 K-tiles (BK=64): A1 = x converted in-reg (T14 split) -> LDS,
//           B1 = w1p rows [c*256,+256) via pre-swizzled global_load_lds.
//   handoff: acc1 -> bias/relu/bf16 -> h1c LDS (64 KB, XOR-swizzled).
//   stage2: 4 K2-tiles x 2 passes (out cols p*256), acc2[2][4][4] persistent.
// LDS: A1 2x16KB | B shared 2x32KB (B1 db / B2 halves) | h1c 64KB = 160 KiB.
__global__ __launch_bounds__(512, 1) void fused(
    const float* __restrict__ x, const ushort* __restrict__ w1p,
    const ushort* __restrict__ w2m, const float* __restrict__ bias1,
    const float* __restrict__ bias2, float* __restrict__ out) {
  __shared__ uint4 ldsq[10240];        // 163840 B
  char* const LA = (char*)ldsq;        // A1: 2 x 16384
  char* const LB = LA + 32768;         // B:  2 x 32768
  char* const LH = LA + 98304;         // h1c: 65536
  const int tid = threadIdx.x;
  const int lane = tid & 63, wid = tid >> 6;
  const int wr = wid >> 2, wc = wid & 3;   // 2M x 4N
  const int brow = blockIdx.x * 128;

  // staging source (pre-swizzled global, involution with swizzled ds_read)
  const int srow = tid >> 3;                     // 0..63
  const int scol = ((tid & 7) * 16) ^ ((srow & 7) << 4);
  const int ldst = wid * 1024;
  const char* const w1b = (const char*)w1p + (size_t)srow * (KPAD * 2) + scol;
  const char* const w2b = (const char*)w2m + (size_t)srow * (Z1C * 2) + scol;

  // fragment-read ids
  const int rA = lane & 15;
  const int klo = (lane >> 4) * 16;
  const int xs = (rA & 7) << 4;

  // A1 conversion staging: thread -> (row, 16-elem k segment)
  const int arow = tid >> 2;                     // 0..127
  const int akseg = (tid & 3) * 16;              // 0/16/32/48
  const float* const xrow = x + (size_t)(brow + arow) * IN_CH;
  const int aswz = (arow & 7) << 4;
  const int awb = arow * 128 + ((akseg * 2) ^ aswz);
  const int awb2 = arow * 128 + ((akseg * 2 + 16) ^ aswz);

  float2 xv[8];
  auto ldA1 = [&](int kt) {  // issue x loads for tile kt (T14: issue early)
    const int k0 = kt * 64 + akseg;
    if (k0 + 16 <= IN_CH) {
#pragma unroll
      for (int j = 0; j < 8; ++j) xv[j] = *(const float2*)(xrow + k0 + 2 * j);
    } else {
#pragma unroll
      for (int j = 0; j < 8; ++j) {
        int c0 = k0 + 2 * j;
        float a = (c0 < IN_CH) ? xrow[c0] : 0.f;
        float b = (c0 + 1 < IN_CH) ? xrow[c0 + 1] : 0.f;
        xv[j] = make_float2(a, b);
      }
    }
  };
  auto wrA1 = [&](char* dst) {  // convert + ds_write (after MFMAs)
    union { ushort u[16]; uint4 q[2]; } pk;
#pragma unroll
    for (int j = 0; j < 8; ++j) {
      pk.u[2 * j] = f2bf(xv[j].x);
      pk.u[2 * j + 1] = f2bf(xv[j].y);
    }
    *(uint4*)(dst + awb) = pk.q[0];
    *(uint4*)(dst + awb2) = pk.q[1];
  };

  f32x4 acc2[2][4][4] = {};

#pragma unroll 1
  for (int c = 0; c < 4; ++c) {
    // ---------------- stage 1 ----------------
    f32x4 acc1[4][4] = {};
    {
#pragma unroll
      for (int h = 0; h < 4; ++h)
        glds16(w1b + (size_t)(c * 256 + h * 64) * (KPAD * 2),
               LB + h * 8192 + ldst);
      ldA1(0);
      wrA1(LA);
    }
    __syncthreads();

#pragma unroll 1
    for (int kt = 0; kt < 13; ++kt) {
      const int cur = kt & 1, nxt = cur ^ 1;
      if (kt < 12) {
#pragma unroll
        for (int h = 0; h < 4; ++h)
          glds16(w1b + (size_t)(c * 256 + h * 64) * (KPAD * 2) + (kt + 1) * 128,
                 LB + nxt * 32768 + h * 8192 + ldst);
        ldA1(kt + 1);
      }
      const char* Ab = LA + cur * 16384;
      const char* Bb = LB + cur * 32768;
      short8 af[4][2], bg[4][2];
#pragma unroll
      for (int m = 0; m < 4; ++m) {
        const int row = wr * 64 + m * 16 + rA;
        af[m][0] = *(const short8*)(Ab + row * 128 + (klo ^ xs));
        af[m][1] = *(const short8*)(Ab + row * 128 + ((64 + klo) ^ xs));
      }
#pragma unroll
      for (int n = 0; n < 4; ++n) {
        const int row = wc * 64 + n * 16 + rA;
        bg[n][0] = *(const short8*)(Bb + row * 128 + (klo ^ xs));
        bg[n][1] = *(const short8*)(Bb + row * 128 + ((64 + klo) ^ xs));
      }
      __builtin_amdgcn_s_setprio(1);
#pragma unroll
      for (int ks = 0; ks < 2; ++ks)
#pragma unroll
        for (int m = 0; m < 4; ++m)
#pragma unroll
          for (int n = 0; n < 4; ++n)
            acc1[m][n] = MFMA(af[m][ks], bg[n][ks], acc1[m][n]);
      __builtin_amdgcn_s_setprio(0);
      if (kt < 12) wrA1(LA + nxt * 16384);
      __syncthreads();
    }

    // ---------------- handoff: acc1 -> h1c (bias + relu + bf16) ----------------
#pragma unroll
    for (int n = 0; n < 4; ++n) {
      const float bv = bias1[c * 256 + wc * 64 + n * 16 + rA];
      const int C2 = (wc * 64 + n * 16 + rA) * 2;
#pragma unroll
      for (int m = 0; m < 4; ++m)
#pragma unroll
        for (int r = 0; r < 4; ++r) {
          const int R = wr * 64 + m * 16 + (lane >> 4) * 4 + r;
          float v = acc1[m][n][r] + bv;
          v = v > 0.f ? v : 0.f;
          *(ushort*)(LH + ((R * 512 + C2) ^ ((R & 7) << 4))) = f2bf(v);
        }
    }
    __syncthreads();

    // ---------------- stage 2: acc2 += h1c @ w2m_cslice^T ----------------
#pragma unroll 1
    for (int k2 = 0; k2 < 4; ++k2) {
#pragma unroll
      for (int h = 0; h < 4; ++h)
        glds16(w2b + (size_t)(h * 64) * (Z1C * 2) + c * 512 + k2 * 128,
               LB + h * 8192 + ldst);
#pragma unroll
      for (int h = 0; h < 4; ++h)
        glds16(w2b + (size_t)(256 + h * 64) * (Z1C * 2) + c * 512 + k2 * 128,
               LB + 32768 + h * 8192 + ldst);
      __syncthreads();
      short8 af[4][2];
#pragma unroll
      for (int m = 0; m < 4; ++m) {
        const int row = wr * 64 + m * 16 + rA;
        af[m][0] = *(const short8*)(LH + row * 512 + ((k2 * 128 + klo) ^ xs));
        af[m][1] =
            *(const short8*)(LH + row * 512 + ((k2 * 128 + 64 + klo) ^ xs));
      }
      __builtin_amdgcn_s_setprio(1);
#pragma unroll
      for (int p = 0; p < 2; ++p) {
        const char* Bb = LB + p * 32768;
        short8 bg[4][2];
#pragma unroll
        for (int n = 0; n < 4; ++n) {
          const int row = wc * 64 + n * 16 + rA;
          bg[n][0] = *(const short8*)(Bb + row * 128 + (klo ^ xs));
          bg[n][1] = *(const short8*)(Bb + row * 128 + ((64 + klo) ^ xs));
        }
#pragma unroll
        for (int ks = 0; ks < 2; ++ks)
#pragma unroll
          for (int m = 0; m < 4; ++m)
#pragma unroll
            for (int n = 0; n < 4; ++n)
              acc2[p][m][n] = MFMA(af[m][ks], bg[n][ks], acc2[p][m][n]);
      }
      __builtin_amdgcn_s_setprio(0);
      __syncthreads();
    }
  }

  // ---------------- out epilogue ----------------
#pragma unroll
  for (int p = 0; p < 2; ++p)
#pragma unroll
    for (int n = 0; n < 4; ++n) {
      const int col = p * 256 + wc * 64 + n * 16 + rA;
      const float bv = bias2[col];
#pragma unroll
      for (int m = 0; m < 4; ++m)
#pragma unroll
        for (int r = 0; r < 4; ++r) {
          const int row = brow + wr * 64 + m * 16 + (lane >> 4) * 4 + r;
          float v = acc2[p][m][n][r] + bv;
          out[(size_t)row * OUT_C + col] = v > 0.f ? v : 0.f;
        }
    }
}

extern "C" void kernel_launch(void* const* d_in, const int* in_sizes, int n_in,
                              void* d_out, int out_size, void* d_ws, size_t ws_size,
                              hipStream_t stream) {
  (void)in_sizes; (void)n_in; (void)out_size; (void)ws_size;
  const float* x   = (const float*)d_in[0];
  const float* W1  = (const float*)d_in[1];
  const float* b1  = (const float*)d_in[2];
  const float* Wc1 = (const float*)d_in[3];
  const float* bc1 = (const float*)d_in[4];
  const float* W2  = (const float*)d_in[5];
  const float* b2  = (const float*)d_in[6];
  const float* Wc2 = (const float*)d_in[7];
  const float* bc2 = (const float*)d_in[8];
  const float* MW0 = (const float*)d_in[9];
  const float* MW1 = (const float*)d_in[10];

  char* ws = (char*)d_ws;
  ushort* w1p   = (ushort*)ws;                   // 1024*832*2 = 1,703,936
  ushort* w2m   = (ushort*)(ws + 1703936);       //  512*1024*2 = 1,048,576
  float*  bias1 = (float*)(ws + 2752512);        // 4096
  float*  bias2 = (float*)(ws + 2756608);        // 2048

  float* out = (float*)d_out;

  prep1<<<1024, 256, 0, stream>>>(W1, b1, Wc1, bc1, MW0, w1p, bias1);
  prep2<<<512, 256, 0, stream>>>(W2, b2, Wc2, bc2, MW1, w2m, bias2);
  fused<<<256, 512, 0, stream>>>(x, w1p, w2m, bias1, bias2, out);
}

// Round 10
// 189.252 us; speedup vs baseline: 1.5243x; 1.5243x over previous
//
#include <hip/hip_runtime.h>
#include <hip/hip_bf16.h>
#include <stdint.h>

#define IN_CH 794
#define KPAD  832            // 26 * 32
#define Z1C   1024
#define OUT_C 512
#define BATCH 32768

typedef __attribute__((ext_vector_type(8))) short short8;
typedef __attribute__((ext_vector_type(4))) float f32x4;

__device__ __forceinline__ ushort f2bf(float f) {
  uint32_t u = __float_as_uint(f);
  return (ushort)((u + 0x7fffu + ((u >> 16) & 1u)) >> 16);  // RTNE
}

__device__ __forceinline__ void glds16(const void* g, void* l) {
  __builtin_amdgcn_global_load_lds(
      (const __attribute__((address_space(1))) void*)g,
      (__attribute__((address_space(3))) void*)l, 16, 0, 0);
}

#define MFMA(a, b, c) __builtin_amdgcn_mfma_f32_16x16x32_bf16(a, b, c, 0, 0, 0)

// ---------------- prep: masked weights (bf16) + folded bias ----------------
__global__ __launch_bounds__(256) void prep1(
    const float* __restrict__ W1, const float* __restrict__ b1,
    const float* __restrict__ Wc1, const float* __restrict__ bc1,
    const float* __restrict__ MW0, ushort* __restrict__ w1p,
    float* __restrict__ bias1) {
  int z = blockIdx.x, t = threadIdx.x;
  float sum = 0.f;
  for (int i = t; i < KPAD; i += 256) {
    float w = 0.f;
    if (i < IN_CH) {
      float m = MW0[z * IN_CH + i];
      w = W1[z * IN_CH + i] * m;
      sum += Wc1[z * IN_CH + i] * m;
    }
    w1p[z * KPAD + i] = f2bf(w);
  }
#pragma unroll
  for (int o = 32; o > 0; o >>= 1) sum += __shfl_down(sum, o, 64);
  __shared__ float red[4];
  if ((t & 63) == 0) red[t >> 6] = sum;
  __syncthreads();
  if (t == 0) bias1[z] = b1[z] + bc1[z] + red[0] + red[1] + red[2] + red[3];
}

__global__ __launch_bounds__(256) void prep2(
    const float* __restrict__ W2, const float* __restrict__ b2,
    const float* __restrict__ Wc2, const float* __restrict__ bc2,
    const float* __restrict__ MW1, ushort* __restrict__ w2m,
    float* __restrict__ bias2) {
  int z = blockIdx.x, t = threadIdx.x;
  float sum = 0.f;
  for (int i = t; i < Z1C; i += 256) {
    float m = MW1[z * Z1C + i];
    w2m[z * Z1C + i] = f2bf(W2[z * Z1C + i] * m);
    sum += Wc2[z * Z1C + i] * m;
  }
#pragma unroll
  for (int o = 32; o > 0; o >>= 1) sum += __shfl_down(sum, o, 64);
  __shared__ float red[4];
  if ((t & 63) == 0) red[t >> 6] = sum;
  __syncthreads();
  if (t == 0) bias2[z] = b2[z] + bc2[z] + red[0] + red[1] + red[2] + red[3];
}

// =================== fused MADE v3 (reg-budget-sized) ===================
// 512 blocks (2 grid rounds, 1/CU), 512 thr, 8 waves 2Mx4N. Block owns 64
// batch rows. 2 chunks x 512 h1-cols, BK=32. Per-wave: acc1[2][8] +
// acc2[2][8] = 128 acc regs; worst live ~190 <= the 256/wave cap a 512-thr
// block implies (2 waves/SIMD, 512-reg pool -> r7/r8/r9 spills).
// LDS: A1 2x4KB | B 2x32KB (B1/B2 time-shared) | h1c 64KB = 136 KiB.
// Rows are 64B (BK=32): swizzle byte ^= (row&3)<<4; h1c rows 1024B:
// byte ^= (row&7)<<4. Pre-swizzled global sources (rule #21).
__global__ __launch_bounds__(512, 2) void fused(
    const float* __restrict__ x, const ushort* __restrict__ w1p,
    const ushort* __restrict__ w2m, const float* __restrict__ bias1,
    const float* __restrict__ bias2, float* __restrict__ out) {
  __shared__ uint4 ldsq[8704];         // 139264 B
  char* const LA = (char*)ldsq;        // A1: 2 x 4096
  char* const LB = LA + 8192;          // B:  2 x 32768
  char* const LH = LA + 73728;         // h1c: 65536 (64 rows x 1024B)
  const int tid = threadIdx.x;
  const int lane = tid & 63, wid = tid >> 6;
  const int wr = wid >> 2, wc = wid & 3;   // 2M x 4N
  const int brow = blockIdx.x * 64;

  const int rA = lane & 15;
  const int kb = (lane >> 4) * 16;     // byte within 64B K-row

  // glds16 staging ids: dest byte = tid*16 -> row = tid>>2, pos16 = tid&3
  const int g_sw = ((tid >> 2) & 3) << 4;
  const char* const b1s =
      (const char*)w1p + (size_t)(tid >> 2) * 1664 + (((tid & 3) * 16) ^ g_sw);
  const char* const b2s =
      (const char*)w2m + (size_t)(tid >> 2) * 2048 + (((tid & 3) * 16) ^ g_sw);
  const int ldst = wid * 1024;

  // conversion ids: row = tid>>3 (0..63), 4 elems at (tid&7)*4
  const int c_r = tid >> 3;
  const int c_e = (tid & 7) * 4;
  const int c_wb = c_r * 64 + ((((tid & 7) * 8)) ^ ((c_r & 3) << 4));
  const float* const xr = x + (size_t)(brow + c_r) * IN_CH;

  float2 xv0, xv1;
  auto ldx = [&](int kt) {
    const int k0 = kt * 32 + c_e;
    if (k0 + 4 <= IN_CH) {
      xv0 = *(const float2*)(xr + k0);
      xv1 = *(const float2*)(xr + k0 + 2);
    } else {
      xv0.x = (k0 < IN_CH) ? xr[k0] : 0.f;
      xv0.y = (k0 + 1 < IN_CH) ? xr[k0 + 1] : 0.f;
      xv1.x = (k0 + 2 < IN_CH) ? xr[k0 + 2] : 0.f;
      xv1.y = (k0 + 3 < IN_CH) ? xr[k0 + 3] : 0.f;
    }
  };
  auto cvt = [&](char* dst) {
    ushort u[4] = {f2bf(xv0.x), f2bf(xv0.y), f2bf(xv1.x), f2bf(xv1.y)};
    *(uint2*)(dst + c_wb) = *(const uint2*)u;
  };
  auto stgB1 = [&](int c, int kt, int buf) {  // w1p rows [c*512,+512) x 32k
#pragma unroll
    for (int h = 0; h < 4; ++h)
      glds16(b1s + (size_t)(c * 512 + h * 128) * 1664 + (size_t)kt * 64,
             LB + buf * 32768 + h * 8192 + ldst);
  };
  auto stgB2 = [&](int c, int t, int buf) {  // w2m rows [0,512) x 32k slice
#pragma unroll
    for (int h = 0; h < 4; ++h)
      glds16(b2s + (size_t)(h * 128) * 2048 + c * 1024 + (size_t)t * 64,
             LB + buf * 32768 + h * 8192 + ldst);
  };

  f32x4 acc2[2][8] = {};

  // prologue: chunk-0 K-tile 0
  stgB1(0, 0, 0);
  ldx(0);
  cvt(LA);
  __syncthreads();

#pragma unroll 1
  for (int c = 0; c < 2; ++c) {
    // ---------------- stage 1: 26 K-tiles ----------------
    f32x4 acc1[2][8] = {};
#pragma unroll 1
    for (int kt = 0; kt < 26; ++kt) {
      const int cur = kt & 1, nxt = cur ^ 1;
      if (kt < 25) { stgB1(c, kt + 1, nxt); ldx(kt + 1); }
      const char* Ab = LA + cur * 4096;
      const char* Bb = LB + cur * 32768;
      short8 af[2];
#pragma unroll
      for (int m = 0; m < 2; ++m) {
        const int row = wr * 32 + m * 16 + rA;
        af[m] = *(const short8*)(Ab + row * 64 + (kb ^ ((row & 3) << 4)));
      }
      __builtin_amdgcn_s_setprio(1);
#pragma unroll
      for (int n = 0; n < 8; ++n) {
        const int rowb = wc * 128 + n * 16 + rA;
        short8 bg = *(const short8*)(Bb + rowb * 64 + (kb ^ ((rowb & 3) << 4)));
        acc1[0][n] = MFMA(af[0], bg, acc1[0][n]);
        acc1[1][n] = MFMA(af[1], bg, acc1[1][n]);
      }
      __builtin_amdgcn_s_setprio(0);
      if (kt < 25) cvt(LA + nxt * 4096);
      if (kt == 25) stgB2(c, 0, 0);  // buf0 free since kt=24; t=0 prefetch
      __syncthreads();
    }

    // ---------------- handoff: acc1 -> h1c ----------------
#pragma unroll
    for (int n = 0; n < 8; ++n) {
      const int col = wc * 128 + n * 16 + rA;
      const float bv = bias1[c * 512 + col];
      const int C2 = col * 2;
#pragma unroll
      for (int m = 0; m < 2; ++m)
#pragma unroll
        for (int r = 0; r < 4; ++r) {
          const int R = wr * 32 + m * 16 + (lane >> 4) * 4 + r;
          float v = acc1[m][n][r] + bv;
          v = v > 0.f ? v : 0.f;
          *(ushort*)(LH + R * 1024 + (C2 ^ ((R & 7) << 4))) = f2bf(v);
        }
    }
    __syncthreads();

    // ---------------- stage 2: 16 k2-tiles of 32 ----------------
#pragma unroll 1
    for (int t = 0; t < 16; ++t) {
      const int cur = t & 1;
      if (t < 15) {
        stgB2(c, t + 1, cur ^ 1);
      } else if (c == 0) {           // prefetch chunk-1 stage1 tile 0
        stgB1(1, 0, 0);
        ldx(0);
        cvt(LA);
      }
      short8 a2[2];
#pragma unroll
      for (int m = 0; m < 2; ++m) {
        const int row = wr * 32 + m * 16 + rA;
        a2[m] = *(const short8*)(LH + row * 1024 +
                                 ((t * 64 + kb) ^ ((row & 7) << 4)));
      }
      const char* Bb = LB + cur * 32768;
      __builtin_amdgcn_s_setprio(1);
#pragma unroll
      for (int n = 0; n < 8; ++n) {
        const int rowb = wc * 128 + n * 16 + rA;
        short8 bg = *(const short8*)(Bb + rowb * 64 + (kb ^ ((rowb & 3) << 4)));
        acc2[0][n] = MFMA(a2[0], bg, acc2[0][n]);
        acc2[1][n] = MFMA(a2[1], bg, acc2[1][n]);
      }
      __builtin_amdgcn_s_setprio(0);
      __syncthreads();
    }
  }

  // ---------------- out epilogue ----------------
#pragma unroll
  for (int n = 0; n < 8; ++n) {
    const int col = wc * 128 + n * 16 + rA;
    const float bv = bias2[col];
#pragma unroll
    for (int m = 0; m < 2; ++m)
#pragma unroll
      for (int r = 0; r < 4; ++r) {
        const int row = brow + wr * 32 + m * 16 + (lane >> 4) * 4 + r;
        float v = acc2[m][n][r] + bv;
        out[(size_t)row * OUT_C + col] = v > 0.f ? v : 0.f;
      }
  }
}

extern "C" void kernel_launch(void* const* d_in, const int* in_sizes, int n_in,
                              void* d_out, int out_size, void* d_ws, size_t ws_size,
                              hipStream_t stream) {
  (void)in_sizes; (void)n_in; (void)out_size; (void)ws_size;
  const float* x   = (const float*)d_in[0];
  const float* W1  = (const float*)d_in[1];
  const float* b1  = (const float*)d_in[2];
  const float* Wc1 = (const float*)d_in[3];
  const float* bc1 = (const float*)d_in[4];
  const float* W2  = (const float*)d_in[5];
  const float* b2  = (const float*)d_in[6];
  const float* Wc2 = (const float*)d_in[7];
  const float* bc2 = (const float*)d_in[8];
  const float* MW0 = (const float*)d_in[9];
  const float* MW1 = (const float*)d_in[10];

  char* ws = (char*)d_ws;
  ushort* w1p   = (ushort*)ws;                   // 1024*832*2 = 1,703,936
  ushort* w2m   = (ushort*)(ws + 1703936);       //  512*1024*2 = 1,048,576
  float*  bias1 = (float*)(ws + 2752512);        // 4096
  float*  bias2 = (float*)(ws + 2756608);        // 2048

  float* out = (float*)d_out;

  prep1<<<1024, 256, 0, stream>>>(W1, b1, Wc1, bc1, MW0, w1p, bias1);
  prep2<<<512, 256, 0, stream>>>(W2, b2, Wc2, bc2, MW1, w2m, bias2);
  fused<<<512, 512, 0, stream>>>(x, w1p, w2m, bias1, bias2, out);
}

// Round 11
// 185.282 us; speedup vs baseline: 1.5569x; 1.0214x over previous
//
#include <hip/hip_runtime.h>
#include <hip/hip_bf16.h>
#include <stdint.h>

#define IN_CH 794
#define KPAD  832            // 13 * 64
#define Z1C   1024
#define OUT_C 512
#define BATCH 32768

typedef __attribute__((ext_vector_type(8))) short short8;
typedef __attribute__((ext_vector_type(4))) float f32x4;

__device__ __forceinline__ ushort f2bf(float f) {
  uint32_t u = __float_as_uint(f);
  return (ushort)((u + 0x7fffu + ((u >> 16) & 1u)) >> 16);  // RTNE
}

__device__ __forceinline__ void glds16(const void* g, void* l) {
  __builtin_amdgcn_global_load_lds(
      (const __attribute__((address_space(1))) void*)g,
      (__attribute__((address_space(3))) void*)l, 16, 0, 0);
}

#define MFMA(a, b, c) __builtin_amdgcn_mfma_f32_16x16x32_bf16(a, b, c, 0, 0, 0)
#define WAITV(n) asm volatile("s_waitcnt vmcnt(" #n ")" ::: "memory")
#define LGKM0()  asm volatile("s_waitcnt lgkmcnt(0)" ::: "memory")
#define BAR()    __builtin_amdgcn_s_barrier()

// ---------------- prep: masked weights (bf16) + folded bias ----------------
__global__ __launch_bounds__(256) void prep1(
    const float* __restrict__ W1, const float* __restrict__ b1,
    const float* __restrict__ Wc1, const float* __restrict__ bc1,
    const float* __restrict__ MW0, ushort* __restrict__ w1p,
    float* __restrict__ bias1) {
  int z = blockIdx.x, t = threadIdx.x;
  float sum = 0.f;
  for (int i = t; i < KPAD; i += 256) {
    float w = 0.f;
    if (i < IN_CH) {
      float m = MW0[z * IN_CH + i];
      w = W1[z * IN_CH + i] * m;
      sum += Wc1[z * IN_CH + i] * m;
    }
    w1p[z * KPAD + i] = f2bf(w);
  }
#pragma unroll
  for (int o = 32; o > 0; o >>= 1) sum += __shfl_down(sum, o, 64);
  __shared__ float red[4];
  if ((t & 63) == 0) red[t >> 6] = sum;
  __syncthreads();
  if (t == 0) bias1[z] = b1[z] + bc1[z] + red[0] + red[1] + red[2] + red[3];
}

__global__ __launch_bounds__(256) void prep2(
    const float* __restrict__ W2, const float* __restrict__ b2,
    const float* __restrict__ Wc2, const float* __restrict__ bc2,
    const float* __restrict__ MW1, ushort* __restrict__ w2m,
    float* __restrict__ bias2) {
  int z = blockIdx.x, t = threadIdx.x;
  float sum = 0.f;
  for (int i = t; i < Z1C; i += 256) {
    float m = MW1[z * Z1C + i];
    w2m[z * Z1C + i] = f2bf(W2[z * Z1C + i] * m);
    sum += Wc2[z * Z1C + i] * m;
  }
#pragma unroll
  for (int o = 32; o > 0; o >>= 1) sum += __shfl_down(sum, o, 64);
  __shared__ float red[4];
  if ((t & 63) == 0) red[t >> 6] = sum;
  __syncthreads();
  if (t == 0) bias2[z] = b2[z] + bc2[z] + red[0] + red[1] + red[2] + red[3];
}

// =================== fused MADE v4: counted-vmcnt pipeline ===================
// 512 blocks (2 rounds), 512 thr, 8 waves 2Mx4N. Block = 64 batch rows.
// 4 chunks x 256 h1-cols; BK=64 (128B rows, conflict-free (row&7)<<4 swizzle).
// LDS: B 3x32KB (triple, depth-2 prefetch) | A 2x8KB (cvt-staged) | h1c 32KB
// = 147456 B. Unit = {gloads+1 B-stage -> ds_read+16 MFMA -> vmcnt(4) ->
// cvt+lgkm0 -> barrier}; vmcnt never drains to 0 in steady state (T3+T4).
// Transitions (ledger-simulated): kt=11/12 stage B2 u0/u1; stage2 u=6/7
// stage next chunk's x + B1(0)/B1(1). acc: acc1 32 + acc2 64 regs.
__global__ __launch_bounds__(512, 2) void fused(
    const float* __restrict__ x, const ushort* __restrict__ w1p,
    const ushort* __restrict__ w2m, const float* __restrict__ bias1,
    const float* __restrict__ bias2, float* __restrict__ out) {
  __shared__ uint4 ldsq[9216];         // 147456 B
  char* const LB = (char*)ldsq;        // B: 3 x 32768
  char* const LA = LB + 98304;         // A: 2 x 8192
  char* const LH = LB + 114688;        // h1c: 32768 (64 rows x 512B)
  const int tid = threadIdx.x, lane = tid & 63, wid = tid >> 6;
  const int wr = wid >> 2, wc = wid & 3;   // 2M x 4N
  const int brow = blockIdx.x * 64;

  const int rA = lane & 15;
  const int klo = (lane >> 4) * 16;
  const int xs = (rA & 7) << 4;

  // staging ids: thread -> (row sr in 64-row substage, 16B seg), pre-swizzled
  const int sr = tid >> 3;
  const int ssw = (sr & 7) << 4;
  const int sx = ((tid & 7) * 16) ^ ssw;
  const int ldst = tid * 16;
  const char* const w1s = (const char*)w1p + (size_t)sr * 1664 + sx;
  const char* const w2s = (const char*)w2m + (size_t)sr * 2048 + sx;

  // x conversion ids: row sr, 8 elems at (tid&7)*8
  const float* const xr = x + (size_t)(brow + sr) * IN_CH;
  const int cwb = sr * 128 + (((tid & 7) * 16) ^ ssw);

  auto stgB1 = [&](int c, int kt, int buf) {
#pragma unroll
    for (int h = 0; h < 4; ++h)
      glds16(w1s + (size_t)(c * 256 + h * 64) * 1664 + kt * 128,
             LB + buf * 32768 + h * 8192 + ldst);
  };
  auto stgB2 = [&](int c, int k2, int p, int buf) {
#pragma unroll
    for (int h = 0; h < 4; ++h)
      glds16(w2s + (size_t)(p * 256 + h * 64) * 2048 + c * 512 + k2 * 128,
             LB + buf * 32768 + h * 8192 + ldst);
  };

  float2 xv[4];
  auto ldx = [&](int kt) {  // 4 x 8B loads (x rows are 8B-aligned)
    const int k0 = kt * 64 + (tid & 7) * 8;
    if (k0 + 8 <= IN_CH) {
#pragma unroll
      for (int j = 0; j < 4; ++j) xv[j] = *(const float2*)(xr + k0 + 2 * j);
    } else {
#pragma unroll
      for (int j = 0; j < 4; ++j) {
        int e = k0 + 2 * j;
        xv[j].x = (e < IN_CH) ? xr[e] : 0.f;
        xv[j].y = (e + 1 < IN_CH) ? xr[e + 1] : 0.f;
      }
    }
  };
  auto cvt = [&](int abuf) {  // pack 8 bf16, one ds_write_b128
    union { ushort u[8]; uint4 q; } pk;
#pragma unroll
    for (int j = 0; j < 4; ++j) {
      pk.u[2 * j] = f2bf(xv[j].x);
      pk.u[2 * j + 1] = f2bf(xv[j].y);
    }
    *(uint4*)(LA + abuf * 8192 + cwb) = pk.q;
  };

  f32x4 acc2[2][2][4] = {};  // [p][m][n]

  auto s1mfma = [&](f32x4(&acc1)[2][4], int bbuf, int abuf) {
    const char* Ab = LA + abuf * 8192;
    const char* Bb = LB + bbuf * 32768;
    short8 af[2][2];
#pragma unroll
    for (int m = 0; m < 2; ++m) {
      const int row = wr * 32 + m * 16 + rA;
#pragma unroll
      for (int ks = 0; ks < 2; ++ks)
        af[m][ks] = *(const short8*)(Ab + row * 128 + ((ks * 64 + klo) ^ xs));
    }
    __builtin_amdgcn_s_setprio(1);
#pragma unroll
    for (int n = 0; n < 4; ++n) {
      const int row = wc * 64 + n * 16 + rA;
#pragma unroll
      for (int ks = 0; ks < 2; ++ks) {
        short8 bg = *(const short8*)(Bb + row * 128 + ((ks * 64 + klo) ^ xs));
        acc1[0][n] = MFMA(af[0][ks], bg, acc1[0][n]);
        acc1[1][n] = MFMA(af[1][ks], bg, acc1[1][n]);
      }
    }
    __builtin_amdgcn_s_setprio(0);
  };

#pragma unroll 1
  for (int c = 0; c < 4; ++c) {
    if (c == 0) {  // prologue: X(0), B1(0)->buf0, B1(1)->buf1
      ldx(0);
      stgB1(0, 0, 0);
      stgB1(0, 1, 1);
      WAITV(8);        // X(0) done
      cvt(0);
      WAITV(4);        // B1(0) done (B1(1) in flight)
      LGKM0();
      BAR();
    }
    f32x4 acc1[2][4] = {};

    // ---------------- stage 1: 13 units ----------------
#pragma unroll 1
    for (int kt = 0; kt < 13; ++kt) {
      if (kt < 12) ldx(kt + 1);
      if (kt < 11)
        stgB1(c, kt + 2, (kt + 2) % 3);
      else if (kt == 11)
        stgB2(c, 0, 0, 1);   // u0 -> buf (13)%3 = 1
      else
        stgB2(c, 0, 1, 2);   // u1 -> buf 2
      s1mfma(acc1, kt % 3, kt & 1);
      WAITV(4);              // B(kt+1) + X(kt+1) done; last stage in flight
      if (kt < 12) { cvt((kt + 1) & 1); LGKM0(); }
      BAR();
    }

    // ---------------- handoff: acc1 -> h1c ----------------
#pragma unroll
    for (int n = 0; n < 4; ++n) {
      const int col = wc * 64 + n * 16 + rA;
      const float bv = bias1[c * 256 + col];
#pragma unroll
      for (int m = 0; m < 2; ++m)
#pragma unroll
        for (int r = 0; r < 4; ++r) {
          const int R = wr * 32 + m * 16 + (lane >> 4) * 4 + r;
          float v = acc1[m][n][r] + bv;
          v = v > 0.f ? v : 0.f;
          *(ushort*)(LH + R * 512 + ((col * 2) ^ ((R & 7) << 4))) = f2bf(v);
        }
    }
    LGKM0();
    BAR();

    // ---------------- stage 2: 8 units (k2 0..3 x pass 0..1) ----------------
#pragma unroll
    for (int u = 0; u < 8; ++u) {
      if (c < 3 && u == 6) ldx(0);                       // next chunk X(0)
      if (u < 6)
        stgB2(c, (u + 2) >> 1, (u + 2) & 1, (15 + u) % 3);
      else if (c < 3 && u == 6)
        stgB1(c + 1, 0, 0);
      else if (c < 3 && u == 7)
        stgB1(c + 1, 1, 1);
      {  // compute unit u from buf (13+u)%3
        const int k2 = u >> 1, p = u & 1;
        const char* Bb = LB + ((13 + u) % 3) * 32768;
        short8 a2[2][2];
#pragma unroll
        for (int m = 0; m < 2; ++m) {
          const int row = wr * 32 + m * 16 + rA;
#pragma unroll
          for (int ks = 0; ks < 2; ++ks)
            a2[m][ks] = *(const short8*)(LH + row * 512 +
                                         ((k2 * 128 + ks * 64 + klo) ^ xs));
        }
        __builtin_amdgcn_s_setprio(1);
#pragma unroll
        for (int n = 0; n < 4; ++n) {
          const int row = wc * 64 + n * 16 + rA;
#pragma unroll
          for (int ks = 0; ks < 2; ++ks) {
            short8 bg =
                *(const short8*)(Bb + row * 128 + ((ks * 64 + klo) ^ xs));
            acc2[p][0][n] = MFMA(a2[0][ks], bg, acc2[p][0][n]);
            acc2[p][1][n] = MFMA(a2[1][ks], bg, acc2[p][1][n]);
          }
        }
        __builtin_amdgcn_s_setprio(0);
      }
      if (u < 6) {
        WAITV(4);
      } else if (u == 6) {
        if (c < 3) { WAITV(8); } else { WAITV(0); }
      } else if (c < 3) {  // u == 7
        WAITV(4);
        cvt(0);
        LGKM0();
      }
      if (!(c == 3 && u == 7)) BAR();
    }
  }

  // ---------------- out epilogue ----------------
#pragma unroll
  for (int p = 0; p < 2; ++p)
#pragma unroll
    for (int n = 0; n < 4; ++n) {
      const int col = p * 256 + wc * 64 + n * 16 + rA;
      const float bv = bias2[col];
#pragma unroll
      for (int m = 0; m < 2; ++m)
#pragma unroll
        for (int r = 0; r < 4; ++r) {
          const int row = brow + wr * 32 + m * 16 + (lane >> 4) * 4 + r;
          float v = acc2[p][m][n][r] + bv;
          out[(size_t)row * OUT_C + col] = v > 0.f ? v : 0.f;
        }
    }
}

extern "C" void kernel_launch(void* const* d_in, const int* in_sizes, int n_in,
                              void* d_out, int out_size, void* d_ws, size_t ws_size,
                              hipStream_t stream) {
  (void)in_sizes; (void)n_in; (void)out_size; (void)ws_size;
  const float* x   = (const float*)d_in[0];
  const float* W1  = (const float*)d_in[1];
  const float* b1  = (const float*)d_in[2];
  const float* Wc1 = (const float*)d_in[3];
  const float* bc1 = (const float*)d_in[4];
  const float* W2  = (const float*)d_in[5];
  const float* b2  = (const float*)d_in[6];
  const float* Wc2 = (const float*)d_in[7];
  const float* bc2 = (const float*)d_in[8];
  const float* MW0 = (const float*)d_in[9];
  const float* MW1 = (const float*)d_in[10];

  char* ws = (char*)d_ws;
  ushort* w1p   = (ushort*)ws;                   // 1024*832*2
  ushort* w2m   = (ushort*)(ws + 1703936);       //  512*1024*2
  float*  bias1 = (float*)(ws + 2752512);
  float*  bias2 = (float*)(ws + 2756608);

  float* out = (float*)d_out;

  prep1<<<1024, 256, 0, stream>>>(W1, b1, Wc1, bc1, MW0, w1p, bias1);
  prep2<<<512, 256, 0, stream>>>(W2, b2, Wc2, bc2, MW1, w2m, bias2);
  fused<<<512, 512, 0, stream>>>(x, w1p, w2m, bias1, bias2, out);
}

// Round 13
// 134.813 us; speedup vs baseline: 2.1398x; 1.3744x over previous
//
#include <hip/hip_runtime.h>
#include <hip/hip_bf16.h>
#include <stdint.h>

#define IN_CH 794
#define KPAD  832            // 13 * 64
#define Z1C   1024
#define OUT_C 512
#define BATCH 32768

typedef __attribute__((ext_vector_type(8))) short short8;
typedef __attribute__((ext_vector_type(4))) float f32x4;

__device__ __forceinline__ ushort f2bf(float f) {
  uint32_t u = __float_as_uint(f);
  return (ushort)((u + 0x7fffu + ((u >> 16) & 1u)) >> 16);  // RTNE
}

__device__ __forceinline__ void glds16(const void* g, void* l) {
  __builtin_amdgcn_global_load_lds(
      (const __attribute__((address_space(1))) void*)g,
      (__attribute__((address_space(3))) void*)l, 16, 0, 0);
}

#define BAR() __builtin_amdgcn_s_barrier()
#define MFMA(a, b, c) __builtin_amdgcn_mfma_f32_16x16x32_bf16(a, b, c, 0, 0, 0)

// ---------------- prep: masked weights (bf16) + folded bias ----------------
__global__ __launch_bounds__(256) void prep1(
    const float* __restrict__ W1, const float* __restrict__ b1,
    const float* __restrict__ Wc1, const float* __restrict__ bc1,
    const float* __restrict__ MW0, ushort* __restrict__ w1p,
    float* __restrict__ bias1) {
  int z = blockIdx.x, t = threadIdx.x;
  float sum = 0.f;
  for (int i = t; i < KPAD; i += 256) {
    float w = 0.f;
    if (i < IN_CH) {
      float m = MW0[z * IN_CH + i];
      w = W1[z * IN_CH + i] * m;
      sum += Wc1[z * IN_CH + i] * m;
    }
    w1p[z * KPAD + i] = f2bf(w);
  }
#pragma unroll
  for (int o = 32; o > 0; o >>= 1) sum += __shfl_down(sum, o, 64);
  __shared__ float red[4];
  if ((t & 63) == 0) red[t >> 6] = sum;
  __syncthreads();
  if (t == 0) bias1[z] = b1[z] + bc1[z] + red[0] + red[1] + red[2] + red[3];
}

__global__ __launch_bounds__(256) void prep2(
    const float* __restrict__ W2, const float* __restrict__ b2,
    const float* __restrict__ Wc2, const float* __restrict__ bc2,
    const float* __restrict__ MW1, ushort* __restrict__ w2m,
    float* __restrict__ bias2) {
  int z = blockIdx.x, t = threadIdx.x;
  float sum = 0.f;
  for (int i = t; i < Z1C; i += 256) {
    float m = MW1[z * Z1C + i];
    w2m[z * Z1C + i] = f2bf(W2[z * Z1C + i] * m);
    sum += Wc2[z * Z1C + i] * m;
  }
#pragma unroll
  for (int o = 32; o > 0; o >>= 1) sum += __shfl_down(sum, o, 64);
  __shared__ float red[4];
  if ((t & 63) == 0) red[t >> 6] = sum;
  __syncthreads();
  if (t == 0) bias2[z] = b2[z] + bc2[z] + red[0] + red[1] + red[2] + red[3];
}

// ---------------- xcvt: x f32 [B,794] -> xb bf16 [B,832] (zero-padded) ----------------
__global__ __launch_bounds__(256) void xcvt(const float* __restrict__ x,
                                            ushort* __restrict__ xb) {
  const int CPR = KPAD / 8;
  const int total = BATCH * CPR;
  for (int i = blockIdx.x * 256 + threadIdx.x; i < total;
       i += gridDim.x * 256) {
    int row = i / CPR;
    int col = (i - row * CPR) * 8;
    const float* p = x + (size_t)row * IN_CH + col;
    ushort u[8];
    if (col + 8 <= IN_CH) {
#pragma unroll
      for (int j = 0; j < 4; ++j) {
        float2 v = *(const float2*)(p + j * 2);
        u[j * 2] = f2bf(v.x);
        u[j * 2 + 1] = f2bf(v.y);
      }
    } else {
#pragma unroll
      for (int j = 0; j < 8; ++j) u[j] = (col + j < IN_CH) ? f2bf(p[j]) : 0;
    }
    *(uint4*)(xb + (size_t)row * KPAD + col) = *(uint4*)u;
  }
}

// ======== 256x256 4-phase pipelined GEMM, A triple-buffered / B double ========
// (r5-proven structure; only the BF16OUT epilogue changed: LDS-restaged
//  coalesced writes to kill the 2x partial-line write amplification.)
template <int KP, int NKT, int NCB, int OSTR, bool BF16OUT>
__global__ __launch_bounds__(512, 2) void gemmT(
    const ushort* __restrict__ Ag, const ushort* __restrict__ Bg,
    const float* __restrict__ bias, void* __restrict__ Cout) {
  __shared__ uint4 ldsq[10240];        // 163840 B
  char* const L = (char*)ldsq;         // A bufs: 3 x 32 KB
  char* const LB = L + 98304;          // B bufs: 2 x 32 KB
  const int tid = threadIdx.x;
  const int lane = tid & 63, wid = tid >> 6;
  const int wr = wid >> 2, wc = wid & 3;      // 2M x 4N

  // T1: bijective XCD chunk swizzle (nwg % 8 == 0)
  const int nwg = gridDim.x;
  const int w0 = blockIdx.x;
  const int swz = (w0 & 7) * (nwg >> 3) + (w0 >> 3);
  const int bcol = (swz % NCB) * 256;
  const int brow = (swz / NCB) * 256;

  // staging source (pre-swizzled global, rule #21)
  const int srow = tid >> 3;                   // 0..63
  const int scol = ((tid & 7) * 16) ^ ((srow & 7) << 4);
  const char* gAp = (const char*)Ag + (size_t)(brow + srow) * (KP * 2) + scol;
  const char* gBp = (const char*)Bg + (size_t)(bcol + srow) * (KP * 2) + scol;
  const int ldst = wid * 1024;

  auto stA = [&](int buf, int kt, int h) {
    glds16(gAp + (size_t)h * (64 * KP * 2) + (size_t)kt * 128,
           L + buf * 32768 + h * 8192 + ldst);
  };
  auto stB = [&](int buf, int kt, int h) {
    glds16(gBp + (size_t)h * (64 * KP * 2) + (size_t)kt * 128,
           LB + buf * 32768 + h * 8192 + ldst);
  };

  // fragment reads (swizzled ds_read_b128)
  const int rA = lane & 15;
  const int klo = (lane >> 4) * 16;
  const int xs = (rA & 7) << 4;
  auto rdA = [&](const char* Ab, int m, int ks) -> short8 {
    int row = wr * 128 + m * 16 + rA;
    return *(const short8*)(Ab + row * 128 + ((ks * 64 + klo) ^ xs));
  };
  auto rdB = [&](const char* Bb, int n, int ks) -> short8 {
    int row = wc * 64 + n * 16 + rA;
    return *(const short8*)(Bb + row * 128 + ((ks * 64 + klo) ^ xs));
  };

  f32x4 acc[8][4] = {};

  // prologue: stage A0->bufA0, B0->bufB0, A1->bufA1; wait A0,B0 (A1 in flight)
#pragma unroll
  for (int h = 0; h < 4; ++h) stA(0, 0, h);
#pragma unroll
  for (int h = 0; h < 4; ++h) stB(0, 0, h);
#pragma unroll
  for (int h = 0; h < 4; ++h) stA(1, 1, h);
  asm volatile("s_waitcnt vmcnt(4)" ::: "memory");
  BAR();

  for (int j = 0; j < NKT; ++j) {
    const char* Ab = L + (j % 3) * 32768;
    const char* Bb = LB + (j & 1) * 32768;
    const int jn = j + 1, ja = j + 2;
    const int bb1 = jn & 1, ab2 = ja % 3;
    short8 aF[4][2], bF[4][2];

    // ---- phase 0: A m0-3 frags, B n0-1 frags; stage B(j+1) h0-1 ----
#pragma unroll
    for (int m = 0; m < 4; ++m) {
      aF[m][0] = rdA(Ab, m, 0); aF[m][1] = rdA(Ab, m, 1);
    }
#pragma unroll
    for (int n = 0; n < 2; ++n) {
      bF[n][0] = rdB(Bb, n, 0); bF[n][1] = rdB(Bb, n, 1);
    }
    if (jn < NKT) { stB(bb1, jn, 0); stB(bb1, jn, 1); }
    BAR();
    __builtin_amdgcn_s_setprio(1);
#pragma unroll
    for (int ks = 0; ks < 2; ++ks)
#pragma unroll
      for (int m = 0; m < 4; ++m)
#pragma unroll
        for (int n = 0; n < 2; ++n)
          acc[m][n] = MFMA(aF[m][ks], bF[n][ks], acc[m][n]);
    __builtin_amdgcn_s_setprio(0);
    BAR();

    // ---- phase 1: B n2-3 frags; stage B(j+1) h2-3 ----
#pragma unroll
    for (int n = 2; n < 4; ++n) {
      bF[n][0] = rdB(Bb, n, 0); bF[n][1] = rdB(Bb, n, 1);
    }
    if (jn < NKT) { stB(bb1, jn, 2); stB(bb1, jn, 3); }
    BAR();
    __builtin_amdgcn_s_setprio(1);
#pragma unroll
    for (int ks = 0; ks < 2; ++ks)
#pragma unroll
      for (int m = 0; m < 4; ++m)
#pragma unroll
        for (int n = 2; n < 4; ++n)
          acc[m][n] = MFMA(aF[m][ks], bF[n][ks], acc[m][n]);
    __builtin_amdgcn_s_setprio(0);
    BAR();

    // ---- phase 2: A m4-7 frags; stage A(j+2) h0-1; reuse B n0-1 ----
#pragma unroll
    for (int m = 0; m < 4; ++m) {
      aF[m][0] = rdA(Ab, m + 4, 0); aF[m][1] = rdA(Ab, m + 4, 1);
    }
    if (ja < NKT) { stA(ab2, ja, 0); stA(ab2, ja, 1); }
    BAR();
    __builtin_amdgcn_s_setprio(1);
#pragma unroll
    for (int ks = 0; ks < 2; ++ks)
#pragma unroll
      for (int m = 0; m < 4; ++m)
#pragma unroll
        for (int n = 0; n < 2; ++n)
          acc[m + 4][n] = MFMA(aF[m][ks], bF[n][ks], acc[m + 4][n]);
    __builtin_amdgcn_s_setprio(0);
    BAR();

    // ---- phase 3: stage A(j+2) h2-3; reuse A m4-7, B n2-3; vmcnt(4) ----
    if (ja < NKT) { stA(ab2, ja, 2); stA(ab2, ja, 3); }
    BAR();
    __builtin_amdgcn_s_setprio(1);
#pragma unroll
    for (int ks = 0; ks < 2; ++ks)
#pragma unroll
      for (int m = 0; m < 4; ++m)
#pragma unroll
        for (int n = 2; n < 4; ++n)
          acc[m + 4][n] = MFMA(aF[m][ks], bF[n][ks], acc[m + 4][n]);
    __builtin_amdgcn_s_setprio(0);
    if (ja < NKT)
      asm volatile("s_waitcnt vmcnt(4)" ::: "memory");
    else if (jn < NKT)
      asm volatile("s_waitcnt vmcnt(0)" ::: "memory");
    BAR();
  }

  if (BF16OUT) {
    // ---- LDS-restaged coalesced bf16 epilogue (2 halves of 128 rows) ----
    char* const LT = (char*)ldsq;  // 64 KB restage tile [128][512B]
#pragma unroll
    for (int h = 0; h < 2; ++h) {
      if (wr == h) {
#pragma unroll
        for (int n = 0; n < 4; ++n) {
          const int col = wc * 64 + n * 16 + rA;
          const float bv = bias[bcol + col];
#pragma unroll
          for (int m = 0; m < 8; ++m)
#pragma unroll
            for (int r = 0; r < 4; ++r) {
              const int R = m * 16 + (lane >> 4) * 4 + r;
              float v = acc[m][n][r] + bv;
              v = v > 0.f ? v : 0.f;
              *(ushort*)(LT + R * 512 + ((col * 2) ^ ((R & 7) << 4))) = f2bf(v);
            }
        }
      }
      __syncthreads();
#pragma unroll
      for (int it = 0; it < 8; ++it) {
        const int idx = it * 8192 + tid * 16;
        const int R = idx >> 9, cb = idx & 511;
        uint4 v = *(const uint4*)(LT + R * 512 + (cb ^ ((R & 7) << 4)));
        *(uint4*)((char*)Cout + (size_t)(brow + h * 128 + R) * (OSTR * 2) +
                  bcol * 2 + cb) = v;
      }
      if (h == 0) __syncthreads();
    }
  } else {
    // ---- f32 epilogue (64B/16-lane lines, already coalesced) ----
#pragma unroll
    for (int n = 0; n < 4; ++n) {
      const int col = bcol + wc * 64 + n * 16 + rA;
      const float bv = bias[col];
#pragma unroll
      for (int m = 0; m < 8; ++m) {
#pragma unroll
        for (int r = 0; r < 4; ++r) {
          const int row = brow + wr * 128 + m * 16 + (lane >> 4) * 4 + r;
          float v = acc[m][n][r] + bv;
          v = v > 0.f ? v : 0.f;
          ((float*)Cout)[(size_t)row * OSTR + col] = v;
        }
      }
    }
  }
}

// ---------------- GEMM1 fallback (fused conversion, round-1 proven) ----------------
__global__ __launch_bounds__(256, 2) void gemm1_fused(
    const float* __restrict__ x, const ushort* __restrict__ w1p,
    const float* __restrict__ bias1, ushort* __restrict__ h1) {
  __shared__ ushort As[128 * 32];
  __shared__ ushort Bs[128 * 32];
  const int tid = threadIdx.x;
  const int lane = tid & 63, wid = tid >> 6;
  const int wr = wid >> 1, wc = wid & 1;
  const int brow = blockIdx.x * 128;
  const int bcol = blockIdx.y * 128;
  f32x4 acc[4][4] = {};
  const int arow = tid >> 1;
  const int acol0 = (tid & 1) * 16;
  const float* xrow = x + (size_t)(brow + arow) * IN_CH;
  for (int kt = 0; kt < 26; ++kt) {
    const int k0 = kt * 32;
#pragma unroll
    for (int c = 0; c < 2; ++c) {
      int idx16 = (wid * 2 + c) * 64 + lane;
      int row = idx16 >> 2, chunk = idx16 & 3;
      glds16(w1p + (size_t)(bcol + row) * KPAD + k0 + chunk * 8,
             (char*)Bs + (wid * 2 + c) * 1024);
    }
    union { ushort u[16]; uint4 q[2]; } pk;
    if (kt < 24) {
      const float* p = xrow + k0 + acol0;
#pragma unroll
      for (int j = 0; j < 8; ++j) {
        float2 v = *(const float2*)(p + j * 2);
        pk.u[j * 2] = f2bf(v.x);
        pk.u[j * 2 + 1] = f2bf(v.y);
      }
    } else {
#pragma unroll
      for (int j = 0; j < 16; ++j) {
        int col = k0 + acol0 + j;
        pk.u[j] = f2bf(col < IN_CH ? xrow[col] : 0.f);
      }
    }
    *(uint4*)&As[arow * 32 + acol0] = pk.q[0];
    *(uint4*)&As[arow * 32 + acol0 + 8] = pk.q[1];
    __syncthreads();
    const int kb = (lane >> 4) * 8, rA = lane & 15;
    short8 af[4], bfrag[4];
#pragma unroll
    for (int m = 0; m < 4; ++m)
      af[m] = *(const short8*)&As[(wr * 64 + m * 16 + rA) * 32 + kb];
#pragma unroll
    for (int n = 0; n < 4; ++n)
      bfrag[n] = *(const short8*)&Bs[(wc * 64 + n * 16 + rA) * 32 + kb];
#pragma unroll
    for (int m = 0; m < 4; ++m)
#pragma unroll
      for (int n = 0; n < 4; ++n)
        acc[m][n] = MFMA(af[m], bfrag[n], acc[m][n]);
    __syncthreads();
  }
  const int orow0 = brow + wr * 64;
  const int ocol0 = bcol + wc * 64;
#pragma unroll
  for (int n = 0; n < 4; ++n) {
    int col = ocol0 + n * 16 + (lane & 15);
    float bv = bias1[col];
#pragma unroll
    for (int m = 0; m < 4; ++m)
#pragma unroll
      for (int r = 0; r < 4; ++r) {
        int row = orow0 + m * 16 + (lane >> 4) * 4 + r;
        float v = acc[m][n][r] + bv;
        v = v > 0.f ? v : 0.f;
        h1[(size_t)row * Z1C + col] = f2bf(v);
      }
  }
}

extern "C" void kernel_launch(void* const* d_in, const int* in_sizes, int n_in,
                              void* d_out, int out_size, void* d_ws, size_t ws_size,
                              hipStream_t stream) {
  (void)in_sizes; (void)n_in; (void)out_size;
  const float* x   = (const float*)d_in[0];
  const float* W1  = (const float*)d_in[1];
  const float* b1  = (const float*)d_in[2];
  const float* Wc1 = (const float*)d_in[3];
  const float* bc1 = (const float*)d_in[4];
  const float* W2  = (const float*)d_in[5];
  const float* b2  = (const float*)d_in[6];
  const float* Wc2 = (const float*)d_in[7];
  const float* bc2 = (const float*)d_in[8];
  const float* MW0 = (const float*)d_in[9];
  const float* MW1 = (const float*)d_in[10];

  char* ws = (char*)d_ws;
  ushort* w1p   = (ushort*)ws;                   // 1024*832*2 = 1,703,936
  ushort* w2m   = (ushort*)(ws + 1703936);       //  512*1024*2 = 1,048,576
  float*  bias1 = (float*)(ws + 2752512);        // 4096
  float*  bias2 = (float*)(ws + 2756608);        // 2048
  ushort* xb    = (ushort*)(ws + 2758656);       // 32768*832*2 = 54,525,952
  const size_t WS_NEED = 2758656ull + 54525952ull;

  ushort* h1 = (ushort*)d_out;   // 32768x1024 bf16 aliases 32768x512 f32
  float*  out = (float*)d_out;

  prep1<<<1024, 256, 0, stream>>>(W1, b1, Wc1, bc1, MW0, w1p, bias1);
  prep2<<<512, 256, 0, stream>>>(W2, b2, Wc2, bc2, MW1, w2m, bias2);

  if (ws_size >= WS_NEED) {
    xcvt<<<2048, 256, 0, stream>>>(x, xb);
    // M=32768 (128 row blocks) x N=1024 (4 col blocks), K=832 (13 tiles)
    gemmT<KPAD, 13, 4, Z1C, true><<<512, 512, 0, stream>>>(xb, w1p, bias1, h1);
  } else {
    gemm1_fused<<<dim3(256, 8), 256, 0, stream>>>(x, w1p, bias1, h1);
  }
  // M=32768 (128 row blocks) x N=512 (2 col blocks), K=1024 (16 tiles)
  gemmT<Z1C, 16, 2, OUT_C, false><<<256, 512, 0, stream>>>(h1, w2m, bias2, out);
}